// Round 4
// baseline (11346.062 us; speedup 1.0000x reference)
//
#include <hip/hip_runtime.h>
#include <cstdint>

typedef short short8 __attribute__((ext_vector_type(8)));
typedef float floatx4 __attribute__((ext_vector_type(4)));

#define TS 512
#define BB 64
#define HD 1024
#define MROWS (TS * BB) // 32768

__device__ __forceinline__ unsigned short f2bf(float f) {
    uint32_t u = __float_as_uint(f);
    u += 0x7fffu + ((u >> 16) & 1u); // RNE
    return (unsigned short)(u >> 16);
}

__device__ __forceinline__ unsigned long long ald64(const void* p) {
    return __hip_atomic_load((const unsigned long long*)p, __ATOMIC_RELAXED,
                             __HIP_MEMORY_SCOPE_AGENT);
}

// device-scope (MALL-direct) 16B load: bypasses L1/L2 so peer XCDs' sc1
// write-through stores are visible with NO acquire fence.
__device__ __forceinline__ uint4 ld_sc1_u4(const unsigned int* p) {
    uint4 d;
    asm volatile("global_load_dwordx4 %0, %1, off sc0 sc1" : "=&v"(d) : "v"(p));
    return d;
}

// counted wait for the inline-asm load pipeline + scheduler fence (rule #18:
// hipcc may hoist register-only MFMA past an asm waitcnt without the barrier)
#define VMWAIT(N)                                              \
    do {                                                       \
        asm volatile("s_waitcnt vmcnt(" #N ")" ::: "memory");  \
        __builtin_amdgcn_sched_barrier(0);                     \
    } while (0)

// ---------------- fp32 -> bf16 cast (vectorized) ----------------
__global__ __launch_bounds__(256) void cast_f32_bf16(const float* __restrict__ s,
                                                     unsigned short* __restrict__ d, int n4) {
    int i = blockIdx.x * 256 + threadIdx.x;
    if (i >= n4) return;
    float4 v = ((const float4*)s)[i];
    ushort4 o = make_ushort4(f2bf(v.x), f2bf(v.y), f2bf(v.z), f2bf(v.w));
    ((ushort4*)d)[i] = o;
}

// ---------------- input-projection GEMM (layer 0 only) ----------------
__global__ __launch_bounds__(256) void gemm_bt_bias(
    const unsigned short* __restrict__ A, const unsigned short* __restrict__ Bt,
    const float* __restrict__ biasF, const float* __restrict__ biasG,
    float* __restrict__ C, int M, int K)
{
    const int N = 2048;
    __shared__ unsigned short As[128 * 32];
    __shared__ unsigned short Bs[128 * 32];
    int bm = blockIdx.x * 128, bn = blockIdx.y * 128;
    int th = threadIdx.x;
    int wave = th >> 6, lane = th & 63;
    int lrow = lane & 15, quad = lane >> 4;
    int wm = (wave & 1) * 64, wn = (wave >> 1) * 64;
    const unsigned short* Ag = A + (size_t)bm * K;
    const unsigned short* Bg = Bt + (size_t)bn * K;

    floatx4 acc[4][4];
#pragma unroll
    for (int i = 0; i < 4; ++i)
#pragma unroll
        for (int j = 0; j < 4; ++j) acc[i][j] = (floatx4){0.f, 0.f, 0.f, 0.f};

    for (int k0 = 0; k0 < K; k0 += 32) {
        __syncthreads();
#pragma unroll
        for (int jj = 0; jj < 2; ++jj) {
            int c = jj * 256 + th;
            int row = c >> 2, kk = c & 3;
            int ph = (row * 4 + (kk ^ ((row >> 1) & 3))) * 8;
            uint4 va = *(const uint4*)(Ag + (size_t)row * K + k0 + kk * 8);
            uint4 vb = *(const uint4*)(Bg + (size_t)row * K + k0 + kk * 8);
            *(uint4*)(As + ph) = va;
            *(uint4*)(Bs + ph) = vb;
        }
        __syncthreads();
        short8 af[4], bfv[4];
#pragma unroll
        for (int i = 0; i < 4; ++i) {
            int r = wm + i * 16 + lrow;
            af[i] = *(const short8*)(As + (r * 4 + (quad ^ ((r >> 1) & 3))) * 8);
        }
#pragma unroll
        for (int j = 0; j < 4; ++j) {
            int r = wn + j * 16 + lrow;
            bfv[j] = *(const short8*)(Bs + (r * 4 + (quad ^ ((r >> 1) & 3))) * 8);
        }
#pragma unroll
        for (int i = 0; i < 4; ++i)
#pragma unroll
            for (int j = 0; j < 4; ++j)
                acc[i][j] = __builtin_amdgcn_mfma_f32_16x16x32_bf16(af[i], bfv[j], acc[i][j], 0, 0, 0);
    }
#pragma unroll
    for (int j = 0; j < 4; ++j) {
        int col = bn + wn + j * 16 + lrow;
        float bias = (col < 1024) ? (biasF[col] - 1.0f) : biasG[col - 1024];
#pragma unroll
        for (int i = 0; i < 4; ++i) {
            int row0 = bm + wm + i * 16 + quad * 4;
#pragma unroll
            for (int r = 0; r < 4; ++r)
                C[(size_t)(row0 + r) * N + col] = acc[i][j][r] + bias;
        }
    }
}

// ---------------- fused two-layer persistent JANET recurrence ----------------
// Protocol v4: SELF-VALIDATING TAGGED DATA. Rings are u32: lo16 = bf16(h),
// hi16 = step tag. Aligned 4B stores are single-copy atomic -> tag+value arrive
// together; NO drain, NO flags, NO barriers, NO fences on the critical path.
// Producers fire sc1 tagged stores and continue. Consumers read data with sc1
// dwordx4 loads and re-issue chunks whose tags != expected step (the spin IS
// the data read). Per-wave flags remain ONLY for 8-deep ring overwrite
// back-pressure (7-step slack, checked lazily with step-old values).
// All 4 waves of a WG are fully independent pipelines (no intra-WG sync).
__global__ __launch_bounds__(256) void janet_fused(
    const float* __restrict__ P,            // layer0 [T*64, 2048] (pf|pg), ifB0-BETA folded
    const unsigned short* __restrict__ Rf0, const unsigned short* __restrict__ Rg0,
    const float* __restrict__ hbf0, const float* __restrict__ hbg0,
    const unsigned short* __restrict__ Rf1, const unsigned short* __restrict__ Rg1,
    const unsigned short* __restrict__ Wi1, // [2048,1024] bf16: ifW1 rows then igW1 rows
    const float* __restrict__ ifB1, const float* __restrict__ hfB1,
    const float* __restrict__ igB1, const float* __restrict__ hgB1,
    unsigned int* __restrict__ ring0,       // [8][64][1024] u32 tagged, zeroed (tag0 = state0)
    unsigned int* __restrict__ ring1,       // [8][64][1024] u32 tagged, zeroed
    int* flags0, int* flags1,               // [256] per-wave progress, zeroed
    float* __restrict__ Yf32)               // layer1 output fp32 [T,64,1024]
{
    __shared__ unsigned short Wl[4][16 * 1024]; // 128 KiB (L0 uses slices 0,1 only)
    const int wg = blockIdx.x, th = threadIdx.x;
    const bool L1 = wg >= 64;
    const int w = L1 ? (wg - 64) : wg;
    const int wave = th >> 6, lane = th & 63;
    const int lrow = lane & 15, quad = lane >> 4;
    const int c0 = w * 16;
    const int col = c0 + lrow;
    const int myrow = wave * 16 + lrow;
    const int sw = lrow & 7;

    // load weight slices once (XOR-swizzled by (n&7) on 8-elem chunks)
    const int nchunks = L1 ? 8192 : 4096;
    for (int c = th; c < nchunks; c += 256) {
        int g = c >> 11, n = (c >> 7) & 15, k8 = c & 127;
        const unsigned short* src;
        if (L1) src = (g == 0) ? Rf1 : (g == 1) ? Rg1 : (g == 2) ? Wi1 : (Wi1 + (size_t)1024 * 1024);
        else    src = g ? Rg0 : Rf0;
        src += (size_t)(c0 + n) * 1024 + k8 * 8;
        *(uint4*)(&Wl[g][(n * 128 + (k8 ^ (n & 7))) * 8]) = *(const uint4*)src;
    }
    __syncthreads();

    float bF, bG;
    if (L1) { bF = ifB1[col] - 1.0f + hfB1[col]; bG = igB1[col] + hgB1[col]; }
    else    { bF = hbf0[col]; bG = hbg0[col]; }

    const unsigned short* w0 = &Wl[0][lrow << 10];
    const unsigned short* w1 = &Wl[1][lrow << 10];
    const unsigned short* w2 = &Wl[2][lrow << 10];
    const unsigned short* w3 = &Wl[3][lrow << 10];

    float hr[4] = {0.f, 0.f, 0.f, 0.f}; // fp32 master h (b = wave*16+quad*4+r)

    auto min4 = [](unsigned long long a, unsigned long long b) {
        int x0 = (int)a, x1 = (int)(a >> 32), x2 = (int)b, x3 = (int)(b >> 32);
        return min(min(x0, x1), min(x2, x3));
    };

    if (!L1) {
        // ---------------- layer 0 ----------------
        float pf[4], pg[4];
        auto pload = [&](int t, float* pfD, float* pgD) {
            size_t pbase = ((size_t)t * 64 + wave * 16 + quad * 4) * 2048 + col;
#pragma unroll
            for (int r = 0; r < 4; ++r) {
                pfD[r] = P[pbase + (size_t)r * 2048];
                pgD[r] = P[pbase + (size_t)r * 2048 + 1024];
            }
        };
        pload(0, pf, pg);

        for (int t = 0; t < TS; ++t) {
            // lazy back-pressure flags (used ~2us later at store time)
            unsigned long long g0a = ald64(&flags0[lane * 4]);
            unsigned long long g0b = ald64(&flags0[lane * 4 + 2]);
            unsigned long long g1a = ald64(&flags1[lane * 4]);
            unsigned long long g1b = ald64(&flags1[lane * 4 + 2]);

            const unsigned int* hsrc =
                ring0 + ((size_t)(t & 7) << 16) + ((size_t)myrow << 10) + (quad << 3);
            const unsigned teh = (unsigned)t << 16;
            floatx4 aF = {0.f, 0.f, 0.f, 0.f}, aG = {0.f, 0.f, 0.f, 0.f};
            uint4 b[4][8];

            auto issue = [&](int c, uint4* buf) {
#pragma unroll
                for (int i = 0; i < 4; ++i) {
                    const unsigned int* p = hsrc + (c * 4 + i) * 32;
                    buf[2 * i]     = ld_sc1_u4(p);
                    buf[2 * i + 1] = ld_sc1_u4(p + 4);
                }
            };
            auto chk = [&](int c, uint4* buf) {
                int sp = 0;
                while (true) {
                    unsigned acc = 0;
#pragma unroll
                    for (int i = 0; i < 8; ++i)
                        acc |= (buf[i].x ^ teh) | (buf[i].y ^ teh) |
                               (buf[i].z ^ teh) | (buf[i].w ^ teh);
                    if (__all((acc & 0xffff0000u) == 0u)) break;
                    if (++sp > (1 << 20)) break; // bail loudly rather than hang
                    issue(c, buf);
                    VMWAIT(0);
                }
            };
            auto mst = [&](int c, uint4* buf) {
#pragma unroll
                for (int i = 0; i < 4; ++i) {
                    int ks = c * 4 + i;
                    uint4 q;
                    q.x = (buf[2 * i].x & 0xffffu)     | (buf[2 * i].y << 16);
                    q.y = (buf[2 * i].z & 0xffffu)     | (buf[2 * i].w << 16);
                    q.z = (buf[2 * i + 1].x & 0xffffu) | (buf[2 * i + 1].y << 16);
                    q.w = (buf[2 * i + 1].z & 0xffffu) | (buf[2 * i + 1].w << 16);
                    short8 a = *(short8*)&q;
                    int koff = ((((ks << 2) + quad) ^ sw) << 3);
                    aF = __builtin_amdgcn_mfma_f32_16x16x32_bf16(a, *(const short8*)(w0 + koff), aF, 0, 0, 0);
                    aG = __builtin_amdgcn_mfma_f32_16x16x32_bf16(a, *(const short8*)(w1 + koff), aG, 0, 0, 0);
                }
            };

            issue(0, b[0]); issue(1, b[1]); issue(2, b[2]); issue(3, b[3]);
#pragma unroll
            for (int c = 0; c < 8; ++c) {
                if (c <= 4) VMWAIT(24);
                else if (c == 5) VMWAIT(16);
                else if (c == 6) VMWAIT(8);
                else VMWAIT(0);
                chk(c, b[c & 3]);
                mst(c, b[c & 3]);
                if (c + 4 < 8) issue(c + 4, b[c & 3]);
            }

            // back-pressure: peers done reading state t-7 (flags >= ...) before
            // overwriting slot (t+1)&7. Lazy values; reload only if short.
            {
                int m0 = min4(g0a, g0b), m1 = min4(g1a, g1b);
                int sp = 0;
                while (!__all(m0 >= t - 6 && m1 >= t - 7)) {
                    if (++sp > (1 << 20)) break;
                    if (sp > 4) __builtin_amdgcn_s_sleep(1);
                    g0a = ald64(&flags0[lane * 4]);
                    g0b = ald64(&flags0[lane * 4 + 2]);
                    g1a = ald64(&flags1[lane * 4]);
                    g1b = ald64(&flags1[lane * 4 + 2]);
                    m0 = min4(g0a, g0b); m1 = min4(g1a, g1b);
                }
            }

            unsigned int* hd = ring0 + ((size_t)((t + 1) & 7) << 16);
            const unsigned tagw = (unsigned)(t + 1) << 16;
#pragma unroll
            for (int r = 0; r < 4; ++r) {
                int bb = wave * 16 + quad * 4 + r;
                float f = 1.f / (1.f + __expf(-(pf[r] + aF[r] + bF)));
                float xg = pg[r] + aG[r] + bG;
                xg = fminf(fmaxf(xg, -15.f), 15.f);
                float e2 = __expf(2.f * xg);
                float g = (e2 - 1.f) / (e2 + 1.f);
                float hn = f * hr[r] + (1.f - f) * g;
                hr[r] = hn;
                __hip_atomic_store(&hd[(size_t)bb * 1024 + col], tagw | (unsigned)f2bf(hn),
                                   __ATOMIC_RELAXED, __HIP_MEMORY_SCOPE_AGENT);
            }
            // per-wave progress flag: fire and forget (back-pressure only)
            if (lane == 0)
                __hip_atomic_store(&flags0[w * 4 + wave], t + 1, __ATOMIC_RELAXED,
                                   __HIP_MEMORY_SCOPE_AGENT);
            if (t + 1 < TS) pload(t + 1, pf, pg);
        }
    } else {
        // ---------------- layer 1 ----------------
        for (int t = 0; t < TS; ++t) {
            unsigned long long g1a = ald64(&flags1[lane * 4]);
            unsigned long long g1b = ald64(&flags1[lane * 4 + 2]);

            const unsigned int* ysrc =
                ring0 + ((size_t)((t + 1) & 7) << 16) + ((size_t)myrow << 10) + (quad << 3);
            const unsigned int* hsrc =
                ring1 + ((size_t)(t & 7) << 16) + ((size_t)myrow << 10) + (quad << 3);
            const unsigned te1h = (unsigned)(t + 1) << 16; // y0 state t+1
            const unsigned te0h = (unsigned)t << 16;       // h1 state t

            floatx4 aPf = {0.f, 0.f, 0.f, 0.f}, aPg = {0.f, 0.f, 0.f, 0.f};
            floatx4 aF = {0.f, 0.f, 0.f, 0.f},  aG = {0.f, 0.f, 0.f, 0.f};
            uint4 yb[2][8], hb[2][8];

            auto issue1 = [&](int c, uint4* yB, uint4* hB) {
#pragma unroll
                for (int i = 0; i < 4; ++i) {
                    const unsigned int* py = ysrc + (c * 4 + i) * 32;
                    const unsigned int* ph = hsrc + (c * 4 + i) * 32;
                    yB[2 * i]     = ld_sc1_u4(py);
                    yB[2 * i + 1] = ld_sc1_u4(py + 4);
                    hB[2 * i]     = ld_sc1_u4(ph);
                    hB[2 * i + 1] = ld_sc1_u4(ph + 4);
                }
            };
            auto chk1 = [&](int c, uint4* yB, uint4* hB) {
                int sp = 0;
                while (true) {
                    unsigned accy = 0, acch = 0;
#pragma unroll
                    for (int i = 0; i < 8; ++i) {
                        accy |= (yB[i].x ^ te1h) | (yB[i].y ^ te1h) |
                                (yB[i].z ^ te1h) | (yB[i].w ^ te1h);
                        acch |= (hB[i].x ^ te0h) | (hB[i].y ^ te0h) |
                                (hB[i].z ^ te0h) | (hB[i].w ^ te0h);
                    }
                    if (__all(((accy | acch) & 0xffff0000u) == 0u)) break;
                    if (++sp > (1 << 20)) break;
                    issue1(c, yB, hB);
                    VMWAIT(0);
                }
            };
            auto mst1 = [&](int c, uint4* yB, uint4* hB) {
#pragma unroll
                for (int i = 0; i < 4; ++i) {
                    int ks = c * 4 + i;
                    uint4 qy, qh;
                    qy.x = (yB[2 * i].x & 0xffffu)     | (yB[2 * i].y << 16);
                    qy.y = (yB[2 * i].z & 0xffffu)     | (yB[2 * i].w << 16);
                    qy.z = (yB[2 * i + 1].x & 0xffffu) | (yB[2 * i + 1].y << 16);
                    qy.w = (yB[2 * i + 1].z & 0xffffu) | (yB[2 * i + 1].w << 16);
                    qh.x = (hB[2 * i].x & 0xffffu)     | (hB[2 * i].y << 16);
                    qh.y = (hB[2 * i].z & 0xffffu)     | (hB[2 * i].w << 16);
                    qh.z = (hB[2 * i + 1].x & 0xffffu) | (hB[2 * i + 1].y << 16);
                    qh.w = (hB[2 * i + 1].z & 0xffffu) | (hB[2 * i + 1].w << 16);
                    short8 ay = *(short8*)&qy;
                    short8 ah = *(short8*)&qh;
                    int koff = ((((ks << 2) + quad) ^ sw) << 3);
                    aF  = __builtin_amdgcn_mfma_f32_16x16x32_bf16(ah, *(const short8*)(w0 + koff), aF, 0, 0, 0);
                    aG  = __builtin_amdgcn_mfma_f32_16x16x32_bf16(ah, *(const short8*)(w1 + koff), aG, 0, 0, 0);
                    aPf = __builtin_amdgcn_mfma_f32_16x16x32_bf16(ay, *(const short8*)(w2 + koff), aPf, 0, 0, 0);
                    aPg = __builtin_amdgcn_mfma_f32_16x16x32_bf16(ay, *(const short8*)(w3 + koff), aPg, 0, 0, 0);
                }
            };

            issue1(0, yb[0], hb[0]); issue1(1, yb[1], hb[1]);
#pragma unroll
            for (int c = 0; c < 8; ++c) {
                if (c <= 6) VMWAIT(16);
                else VMWAIT(0);
                chk1(c, yb[c & 1], hb[c & 1]);
                mst1(c, yb[c & 1], hb[c & 1]);
                if (c + 2 < 8) issue1(c + 2, yb[c & 1], hb[c & 1]);
            }

            // back-pressure on ring1 slot reuse (peers >= t-6)
            {
                int m1 = min4(g1a, g1b);
                int sp = 0;
                while (!__all(m1 >= t - 6)) {
                    if (++sp > (1 << 20)) break;
                    if (sp > 4) __builtin_amdgcn_s_sleep(1);
                    g1a = ald64(&flags1[lane * 4]);
                    g1b = ald64(&flags1[lane * 4 + 2]);
                    m1 = min4(g1a, g1b);
                }
            }

            unsigned int* hd = ring1 + ((size_t)((t + 1) & 7) << 16);
            const unsigned tagw = (unsigned)(t + 1) << 16;
            float hn4[4];
#pragma unroll
            for (int r = 0; r < 4; ++r) {
                int bb = wave * 16 + quad * 4 + r;
                float f = 1.f / (1.f + __expf(-(aPf[r] + aF[r] + bF)));
                float xg = aPg[r] + aG[r] + bG;
                xg = fminf(fmaxf(xg, -15.f), 15.f);
                float e2 = __expf(2.f * xg);
                float g = (e2 - 1.f) / (e2 + 1.f);
                float hn = f * hr[r] + (1.f - f) * g;
                hr[r] = hn;
                hn4[r] = hn;
                __hip_atomic_store(&hd[(size_t)bb * 1024 + col], tagw | (unsigned)f2bf(hn),
                                   __ATOMIC_RELAXED, __HIP_MEMORY_SCOPE_AGENT);
            }
            if (lane == 0)
                __hip_atomic_store(&flags1[w * 4 + wave], t + 1, __ATOMIC_RELAXED,
                                   __HIP_MEMORY_SCOPE_AGENT);
            // output stores off the critical path
#pragma unroll
            for (int r = 0; r < 4; ++r) {
                int bb = wave * 16 + quad * 4 + r;
                Yf32[((size_t)t * 64 + bb) * 1024 + col] = hn4[r];
            }
        }
    }
}

extern "C" void kernel_launch(void* const* d_in, const int* in_sizes, int n_in,
                              void* d_out, int out_size, void* d_ws, size_t ws_size,
                              hipStream_t stream) {
    (void)in_sizes; (void)n_in; (void)out_size; (void)ws_size;
    const float* X    = (const float*)d_in[0];
    const float* ifW0 = (const float*)d_in[1];
    const float* ifB0 = (const float*)d_in[2];
    const float* hfW0 = (const float*)d_in[3];
    const float* hfB0 = (const float*)d_in[4];
    const float* igW0 = (const float*)d_in[5];
    const float* igB0 = (const float*)d_in[6];
    const float* hgW0 = (const float*)d_in[7];
    const float* hgB0 = (const float*)d_in[8];
    const float* ifW1 = (const float*)d_in[9];
    const float* ifB1 = (const float*)d_in[10];
    const float* hfW1 = (const float*)d_in[11];
    const float* hfB1 = (const float*)d_in[12];
    const float* igW1 = (const float*)d_in[13];
    const float* igB1 = (const float*)d_in[14];
    const float* hgW1 = (const float*)d_in[15];
    const float* hgB1 = (const float*)d_in[16];

    char* p = (char*)d_ws;
    auto alloc = [&](size_t bytes) {
        char* r = p; p += (bytes + 255) & ~(size_t)255; return r;
    };
    float* P            = (float*)alloc((size_t)MROWS * 2048 * 4);          // 256 MB
    unsigned short* Xb  = (unsigned short*)alloc((size_t)MROWS * 512 * 2);  // 32 MB
    unsigned short* W0c = (unsigned short*)alloc((size_t)2048 * 512 * 2);   // GEMM weights L0
    unsigned short* W1c = (unsigned short*)alloc((size_t)2048 * 1024 * 2);  // ifW1|igW1 bf16
    unsigned short* Rf0 = (unsigned short*)alloc((size_t)1024 * 1024 * 2);
    unsigned short* Rg0 = (unsigned short*)alloc((size_t)1024 * 1024 * 2);
    unsigned short* Rf1 = (unsigned short*)alloc((size_t)1024 * 1024 * 2);
    unsigned short* Rg1 = (unsigned short*)alloc((size_t)1024 * 1024 * 2);
    // contiguous zero-init region: ring0 | ring1 | flags0 | flags1
    unsigned int* ring0 = (unsigned int*)alloc((size_t)8 * 64 * 1024 * 4); // 2 MB (tagged u32)
    unsigned int* ring1 = (unsigned int*)alloc((size_t)8 * 64 * 1024 * 4); // 2 MB
    int* flags0 = (int*)alloc(4096);
    int* flags1 = (int*)alloc(4096);

    // ws is poisoned every call: zero rings (tag0 == valid state 0) + flags
    hipMemsetAsync(ring0, 0, (size_t)2 * 2097152 + 4096 + 4096, stream);

    auto cast = [&](const float* s, unsigned short* d, size_t n) {
        int n4 = (int)(n / 4);
        cast_f32_bf16<<<dim3((n4 + 255) / 256), dim3(256), 0, stream>>>(s, d, n4);
    };
    cast(X, Xb, (size_t)MROWS * 512);
    cast(ifW0, W0c, (size_t)1024 * 512);
    cast(igW0, W0c + (size_t)1024 * 512, (size_t)1024 * 512);
    cast(ifW1, W1c, (size_t)1024 * 1024);
    cast(igW1, W1c + (size_t)1024 * 1024, (size_t)1024 * 1024);
    cast(hfW0, Rf0, (size_t)1024 * 1024);
    cast(hgW0, Rg0, (size_t)1024 * 1024);
    cast(hfW1, Rf1, (size_t)1024 * 1024);
    cast(hgW1, Rg1, (size_t)1024 * 1024);

    // layer-0 input projections (layer 1's are computed on the fly in the fused kernel)
    gemm_bt_bias<<<dim3(MROWS / 128, 16), dim3(256), 0, stream>>>(Xb, W0c, ifB0, igB0, P, MROWS, 512);

    // fused two-layer pipelined scan
    janet_fused<<<dim3(128), dim3(256), 0, stream>>>(
        P, Rf0, Rg0, hfB0, hgB0,
        Rf1, Rg1, W1c, ifB1, hfB1, igB1, hgB1,
        ring0, ring1, flags0, flags1, (float*)d_out);
}

// Round 5
// 5209.966 us; speedup vs baseline: 2.1778x; 2.1778x over previous
//
#include <hip/hip_runtime.h>
#include <cstdint>

typedef short short8 __attribute__((ext_vector_type(8)));
typedef float floatx4 __attribute__((ext_vector_type(4)));

#define TS 512
#define BB 64
#define HD 1024
#define MROWS (TS * BB) // 32768

__device__ __forceinline__ unsigned short f2bf(float f) {
    uint32_t u = __float_as_uint(f);
    u += 0x7fffu + ((u >> 16) & 1u); // RNE
    return (unsigned short)(u >> 16);
}

__device__ __forceinline__ void wait_vm0() {
    asm volatile("s_waitcnt vmcnt(0)" ::: "memory");
}

__device__ __forceinline__ void raw_barrier() {
    asm volatile("s_barrier" ::: "memory");
}

// device-scope (MALL-direct) 16B load: bypasses L1/L2 so we need NO acquire
// fence / buffer_inv to see peer XCDs' sc1 write-through stores.
__device__ __forceinline__ void ld_sc1_b128(short8& d, const unsigned short* p) {
    asm volatile("global_load_dwordx4 %0, %1, off sc0 sc1"
                 : "=&v"(d) : "v"(p));
}

// counted wait for the inline-asm load pipeline + scheduler fence (rule #18:
// hipcc may hoist register-only MFMA past an asm waitcnt without the barrier)
#define VMWAIT(N)                                              \
    do {                                                       \
        asm volatile("s_waitcnt vmcnt(" #N ")" ::: "memory");  \
        __builtin_amdgcn_sched_barrier(0);                     \
    } while (0)

// ---------------- fp32 -> bf16 cast (vectorized) ----------------
__global__ __launch_bounds__(256) void cast_f32_bf16(const float* __restrict__ s,
                                                     unsigned short* __restrict__ d, int n4) {
    int i = blockIdx.x * 256 + threadIdx.x;
    if (i >= n4) return;
    float4 v = ((const float4*)s)[i];
    ushort4 o = make_ushort4(f2bf(v.x), f2bf(v.y), f2bf(v.z), f2bf(v.w));
    ((ushort4*)d)[i] = o;
}

// ---------------- input-projection GEMM (layer 0 only) ----------------
// C[M,2048] = A[M,K](bf16) * Bt[2048,K]^T + bias ; cols 0..1023 get biasF-1 (BETA), rest biasG
__global__ __launch_bounds__(256) void gemm_bt_bias(
    const unsigned short* __restrict__ A, const unsigned short* __restrict__ Bt,
    const float* __restrict__ biasF, const float* __restrict__ biasG,
    float* __restrict__ C, int M, int K)
{
    const int N = 2048;
    __shared__ unsigned short As[128 * 32];
    __shared__ unsigned short Bs[128 * 32];
    int bm = blockIdx.x * 128, bn = blockIdx.y * 128;
    int th = threadIdx.x;
    int wave = th >> 6, lane = th & 63;
    int lrow = lane & 15, quad = lane >> 4;
    int wm = (wave & 1) * 64, wn = (wave >> 1) * 64;
    const unsigned short* Ag = A + (size_t)bm * K;
    const unsigned short* Bg = Bt + (size_t)bn * K;

    floatx4 acc[4][4];
#pragma unroll
    for (int i = 0; i < 4; ++i)
#pragma unroll
        for (int j = 0; j < 4; ++j) acc[i][j] = (floatx4){0.f, 0.f, 0.f, 0.f};

    for (int k0 = 0; k0 < K; k0 += 32) {
        __syncthreads();
#pragma unroll
        for (int jj = 0; jj < 2; ++jj) {
            int c = jj * 256 + th;
            int row = c >> 2, kk = c & 3;
            int ph = (row * 4 + (kk ^ ((row >> 1) & 3))) * 8;
            uint4 va = *(const uint4*)(Ag + (size_t)row * K + k0 + kk * 8);
            uint4 vb = *(const uint4*)(Bg + (size_t)row * K + k0 + kk * 8);
            *(uint4*)(As + ph) = va;
            *(uint4*)(Bs + ph) = vb;
        }
        __syncthreads();
        short8 af[4], bfv[4];
#pragma unroll
        for (int i = 0; i < 4; ++i) {
            int r = wm + i * 16 + lrow;
            af[i] = *(const short8*)(As + (r * 4 + (quad ^ ((r >> 1) & 3))) * 8);
        }
#pragma unroll
        for (int j = 0; j < 4; ++j) {
            int r = wn + j * 16 + lrow;
            bfv[j] = *(const short8*)(Bs + (r * 4 + (quad ^ ((r >> 1) & 3))) * 8);
        }
#pragma unroll
        for (int i = 0; i < 4; ++i)
#pragma unroll
            for (int j = 0; j < 4; ++j)
                acc[i][j] = __builtin_amdgcn_mfma_f32_16x16x32_bf16(af[i], bfv[j], acc[i][j], 0, 0, 0);
    }
#pragma unroll
    for (int j = 0; j < 4; ++j) {
        int col = bn + wn + j * 16 + lrow;
        float bias = (col < 1024) ? (biasF[col] - 1.0f) : biasG[col - 1024];
#pragma unroll
        for (int i = 0; i < 4; ++i) {
            int row0 = bm + wm + i * 16 + quad * 4;
#pragma unroll
            for (int r = 0; r < 4; ++r)
                C[(size_t)(row0 + r) * N + col] = acc[i][j][r] + bias;
        }
    }
}

// ---------------- fused two-layer persistent JANET recurrence ----------------
// 128 WGs x 256 threads. WG w<64: layer0 cols [16w,16w+16). WG w>=64: layer1 cols.
// ring0 (8-deep) transports Y0 to layer1; layer1 computes Y0[t]@ifW1/igW1 on the fly.
// Sync protocol v5 (= proven v3 + hot-line fixes):
//   release: per-wave vmcnt(0) drain of sc1 write-through h stores -> raw s_barrier ->
//            thread0 publishes ONE per-WG sc1 flag. Flags are PADDED to one 128B
//            cache line per WG (stride 32 ints): 64 producers write 64 DISTINCT
//            MALL lines (parallel slices) instead of piling into 2 hot lines.
//   acquire: wave0 polls per-WG flags (lane l -> line l), s_sleep backoff; raw
//            s_barrier; NO acquire fence. Ring reads use global_load_dwordx4
//            sc0 sc1 (MALL-direct), pipelined with counted vmcnt.
//   L0 back-pressure on flags1 (ring0 slot reuse, 8-deep) is amortized: checked
//   only when t%4==1 with threshold t-4 (safe: covers steps t..t+3, since step
//   t' needs flags1 >= t'-7 and t0-4 >= t'-7 for t' <= t0+3).
// L1's poll (flags0>=t+1, flags1>=t) already implies its ring reuse safety.
__global__ __launch_bounds__(256) void janet_fused(
    const float* __restrict__ P,            // layer0 [T*64, 2048] (pf|pg), ifB0-BETA folded
    const unsigned short* __restrict__ Rf0, const unsigned short* __restrict__ Rg0,
    const float* __restrict__ hbf0, const float* __restrict__ hbg0,
    const unsigned short* __restrict__ Rf1, const unsigned short* __restrict__ Rg1,
    const unsigned short* __restrict__ Wi1, // [2048,1024] bf16: ifW1 rows then igW1 rows
    const float* __restrict__ ifB1, const float* __restrict__ hfB1,
    const float* __restrict__ igB1, const float* __restrict__ hgB1,
    unsigned short* __restrict__ ring0,     // [8][64][1024] bf16, zeroed
    unsigned short* __restrict__ ring1,     // [2][64][1024] bf16, zeroed
    int* flags0, int* flags1,               // [64*32] each: one 128B line per WG, zeroed
    float* __restrict__ Yf32)               // layer1 output fp32 [T,64,1024]
{
    __shared__ unsigned short Wl[4][16 * 1024]; // 128 KiB (L0 uses slices 0,1 only)
    const int wg = blockIdx.x, th = threadIdx.x;
    const bool L1 = wg >= 64;
    const int w = L1 ? (wg - 64) : wg;
    const int wave = th >> 6, lane = th & 63;
    const int lrow = lane & 15, quad = lane >> 4;
    const int c0 = w * 16;
    const int col = c0 + lrow;
    const int myrow = wave * 16 + lrow;
    const int sw = lrow & 7;

    // load weight slices once (XOR-swizzled by (n&7) on 8-elem chunks)
    const int nchunks = L1 ? 8192 : 4096;
    for (int c = th; c < nchunks; c += 256) {
        int g = c >> 11, n = (c >> 7) & 15, k8 = c & 127;
        const unsigned short* src;
        if (L1) src = (g == 0) ? Rf1 : (g == 1) ? Rg1 : (g == 2) ? Wi1 : (Wi1 + (size_t)1024 * 1024);
        else    src = g ? Rg0 : Rf0;
        src += (size_t)(c0 + n) * 1024 + k8 * 8;
        *(uint4*)(&Wl[g][(n * 128 + (k8 ^ (n & 7))) * 8]) = *(const uint4*)src;
    }
    __syncthreads();

    float bF, bG;
    if (L1) { bF = ifB1[col] - 1.0f + hfB1[col]; bG = igB1[col] + hgB1[col]; }
    else    { bF = hbf0[col]; bG = hbg0[col]; }

    const unsigned short* w0 = &Wl[0][lrow << 10];
    const unsigned short* w1 = &Wl[1][lrow << 10];
    const unsigned short* w2 = &Wl[2][lrow << 10];
    const unsigned short* w3 = &Wl[3][lrow << 10];

    float hr[4] = {0.f, 0.f, 0.f, 0.f}; // fp32 master h (b = wave*16+quad*4+r)

    // acquire: wave0 polls per-WG padded flags (lane l -> line l), others park
    auto pollWG = [&](int th0_, int th1_, bool useBP) {
        if (wave == 0) {
            int spins = 0;
            while (true) {
                int f0 = __hip_atomic_load(&flags0[lane << 5], __ATOMIC_RELAXED,
                                           __HIP_MEMORY_SCOPE_AGENT);
                bool ok;
                if (useBP) {
                    int f1 = __hip_atomic_load(&flags1[lane << 5], __ATOMIC_RELAXED,
                                               __HIP_MEMORY_SCOPE_AGENT);
                    ok = (f0 >= th0_) && (f1 >= th1_);
                } else {
                    ok = (f0 >= th0_);
                }
                if (__all(ok)) break;
                if (++spins > (1 << 20)) break; // bail loudly rather than hang
                if (spins > 8) __builtin_amdgcn_s_sleep(1);
            }
        }
        raw_barrier();
    };

    // release: all waves drain own sc1 stores, then one padded flag per WG
    auto release = [&](int* flags, int v) {
        wait_vm0();
        raw_barrier();
        if (th == 0)
            __hip_atomic_store(&flags[w << 5], v, __ATOMIC_RELAXED, __HIP_MEMORY_SCOPE_AGENT);
    };

    if (!L1) {
        // ---------------- layer 0 ----------------
        float pf[4], pg[4];
        auto pload = [&](int t, float* pfD, float* pgD) {
            size_t pbase = ((size_t)t * 64 + wave * 16 + quad * 4) * 2048 + col;
#pragma unroll
            for (int r = 0; r < 4; ++r) {
                pfD[r] = P[pbase + (size_t)r * 2048];
                pgD[r] = P[pbase + (size_t)r * 2048 + 1024];
            }
        };
        pload(0, pf, pg);

        for (int t = 0; t < TS; ++t) {
            // peers stored h0[t]; flags1 back-pressure amortized (every 4th step)
            if (t) pollWG(t, t - 4, (t & 3) == 1);

            const unsigned short* hs =
                ring0 + ((size_t)(t & 7) << 16) + ((size_t)myrow << 10) + (quad << 3);

            wait_vm0(); // clean vm counter (prefetch long complete) for counted waits
            short8 hA[8], hB[8];
            auto issue = [&](int c, short8* buf) {
#pragma unroll
                for (int i = 0; i < 8; ++i)
                    ld_sc1_b128(buf[i], hs + (((c << 3) + i) << 5));
            };
            floatx4 aF = {0.f, 0.f, 0.f, 0.f}, aG = {0.f, 0.f, 0.f, 0.f};
            auto mchunk = [&](int c, const short8* buf) {
#pragma unroll
                for (int i = 0; i < 8; ++i) {
                    int ks = (c << 3) + i;
                    int koff = ((((ks << 2) + quad) ^ sw) << 3);
                    short8 bf_ = *(const short8*)(w0 + koff);
                    short8 bg_ = *(const short8*)(w1 + koff);
                    aF = __builtin_amdgcn_mfma_f32_16x16x32_bf16(buf[i], bf_, aF, 0, 0, 0);
                    aG = __builtin_amdgcn_mfma_f32_16x16x32_bf16(buf[i], bg_, aG, 0, 0, 0);
                }
            };
            issue(0, hA);
            issue(1, hB);
            VMWAIT(8); mchunk(0, hA); issue(2, hA);
            VMWAIT(8); mchunk(1, hB); issue(3, hB);
            VMWAIT(8); mchunk(2, hA);
            VMWAIT(0); mchunk(3, hB);

            unsigned short* hd = ring0 + ((size_t)((t + 1) & 7) << 16);
#pragma unroll
            for (int r = 0; r < 4; ++r) {
                int b = wave * 16 + quad * 4 + r;
                float f = 1.f / (1.f + __expf(-(pf[r] + aF[r] + bF)));
                float xg = pg[r] + aG[r] + bG;
                xg = fminf(fmaxf(xg, -15.f), 15.f);
                float e2 = __expf(2.f * xg);
                float g = (e2 - 1.f) / (e2 + 1.f);
                float hn = f * hr[r] + (1.f - f) * g;
                hr[r] = hn;
                unsigned short hb = f2bf(hn);
                int partner = __shfl_xor((int)hb, 1, 64);
                if (!(lrow & 1)) {
                    unsigned int pk = (unsigned int)hb | ((unsigned int)partner << 16);
                    __hip_atomic_store((unsigned int*)(hd + (size_t)b * 1024 + col), pk,
                                       __ATOMIC_RELAXED, __HIP_MEMORY_SCOPE_AGENT);
                }
            }
            release(flags0, t + 1);
            if (t + 1 < TS) pload(t + 1, pf, pg); // flies during next poll
        }
    } else {
        // ---------------- layer 1 ----------------
        for (int t = 0; t < TS; ++t) {
            pollWG(t + 1, t, true); // Y0[t] published; peers stored h1[t]

            const unsigned short* ys =
                ring0 + ((size_t)((t + 1) & 7) << 16) + ((size_t)myrow << 10) + (quad << 3);
            const unsigned short* hs =
                ring1 + ((size_t)(t & 1) << 16) + ((size_t)myrow << 10) + (quad << 3);

            wait_vm0(); // clean vm counter (Y stores long complete) for counted waits
            short8 yA[4], yB[4], hA[4], hB[4];
            auto lcI = [&](int c, short8* yb, short8* hb) {
#pragma unroll
                for (int i = 0; i < 4; ++i) {
                    ld_sc1_b128(yb[i], ys + (((c << 2) + i) << 5));
                    ld_sc1_b128(hb[i], hs + (((c << 2) + i) << 5));
                }
            };
            floatx4 aPf = {0.f, 0.f, 0.f, 0.f}, aPg = {0.f, 0.f, 0.f, 0.f};
            floatx4 aF = {0.f, 0.f, 0.f, 0.f},  aG = {0.f, 0.f, 0.f, 0.f};
            auto mc = [&](int c, const short8* yb, const short8* hb) {
#pragma unroll
                for (int i = 0; i < 4; ++i) {
                    int ks = (c << 2) + i;
                    int koff = ((((ks << 2) + quad) ^ sw) << 3);
                    short8 wf_ = *(const short8*)(w0 + koff);
                    short8 wg_ = *(const short8*)(w1 + koff);
                    short8 wif = *(const short8*)(w2 + koff);
                    short8 wig = *(const short8*)(w3 + koff);
                    aF  = __builtin_amdgcn_mfma_f32_16x16x32_bf16(hb[i], wf_, aF, 0, 0, 0);
                    aG  = __builtin_amdgcn_mfma_f32_16x16x32_bf16(hb[i], wg_, aG, 0, 0, 0);
                    aPf = __builtin_amdgcn_mfma_f32_16x16x32_bf16(yb[i], wif, aPf, 0, 0, 0);
                    aPg = __builtin_amdgcn_mfma_f32_16x16x32_bf16(yb[i], wig, aPg, 0, 0, 0);
                }
            };
            lcI(0, yA, hA);
            lcI(1, yB, hB);
            VMWAIT(8); mc(0, yA, hA); lcI(2, yA, hA);
            VMWAIT(8); mc(1, yB, hB); lcI(3, yB, hB);
            VMWAIT(8); mc(2, yA, hA); lcI(4, yA, hA);
            VMWAIT(8); mc(3, yB, hB); lcI(5, yB, hB);
            VMWAIT(8); mc(4, yA, hA); lcI(6, yA, hA);
            VMWAIT(8); mc(5, yB, hB); lcI(7, yB, hB);
            VMWAIT(8); mc(6, yA, hA);
            VMWAIT(0); mc(7, yB, hB);

            unsigned short* hd = ring1 + ((size_t)((t + 1) & 1) << 16);
            float hn4[4];
#pragma unroll
            for (int r = 0; r < 4; ++r) {
                int b = wave * 16 + quad * 4 + r;
                float f = 1.f / (1.f + __expf(-(aPf[r] + aF[r] + bF)));
                float xg = aPg[r] + aG[r] + bG;
                xg = fminf(fmaxf(xg, -15.f), 15.f);
                float e2 = __expf(2.f * xg);
                float g = (e2 - 1.f) / (e2 + 1.f);
                float hn = f * hr[r] + (1.f - f) * g;
                hr[r] = hn;
                hn4[r] = hn;
                unsigned short hb = f2bf(hn);
                int partner = __shfl_xor((int)hb, 1, 64);
                if (!(lrow & 1)) {
                    unsigned int pk = (unsigned int)hb | ((unsigned int)partner << 16);
                    __hip_atomic_store((unsigned int*)(hd + (size_t)b * 1024 + col), pk,
                                       __ATOMIC_RELAXED, __HIP_MEMORY_SCOPE_AGENT);
                }
            }
            release(flags1, t + 1);
            // Y stores after release: off the drain critical path
#pragma unroll
            for (int r = 0; r < 4; ++r) {
                int b = wave * 16 + quad * 4 + r;
                Yf32[((size_t)t * 64 + b) * 1024 + col] = hn4[r];
            }
        }
    }
}

extern "C" void kernel_launch(void* const* d_in, const int* in_sizes, int n_in,
                              void* d_out, int out_size, void* d_ws, size_t ws_size,
                              hipStream_t stream) {
    (void)in_sizes; (void)n_in; (void)out_size; (void)ws_size;
    const float* X    = (const float*)d_in[0];
    const float* ifW0 = (const float*)d_in[1];
    const float* ifB0 = (const float*)d_in[2];
    const float* hfW0 = (const float*)d_in[3];
    const float* hfB0 = (const float*)d_in[4];
    const float* igW0 = (const float*)d_in[5];
    const float* igB0 = (const float*)d_in[6];
    const float* hgW0 = (const float*)d_in[7];
    const float* hgB0 = (const float*)d_in[8];
    const float* ifW1 = (const float*)d_in[9];
    const float* ifB1 = (const float*)d_in[10];
    const float* hfW1 = (const float*)d_in[11];
    const float* hfB1 = (const float*)d_in[12];
    const float* igW1 = (const float*)d_in[13];
    const float* igB1 = (const float*)d_in[14];
    const float* hgW1 = (const float*)d_in[15];
    const float* hgB1 = (const float*)d_in[16];

    char* p = (char*)d_ws;
    auto alloc = [&](size_t bytes) {
        char* r = p; p += (bytes + 255) & ~(size_t)255; return r;
    };
    float* P            = (float*)alloc((size_t)MROWS * 2048 * 4);          // 256 MB
    unsigned short* Xb  = (unsigned short*)alloc((size_t)MROWS * 512 * 2);  // 32 MB
    unsigned short* W0c = (unsigned short*)alloc((size_t)2048 * 512 * 2);   // GEMM weights L0
    unsigned short* W1c = (unsigned short*)alloc((size_t)2048 * 1024 * 2);  // ifW1|igW1 bf16
    unsigned short* Rf0 = (unsigned short*)alloc((size_t)1024 * 1024 * 2);
    unsigned short* Rg0 = (unsigned short*)alloc((size_t)1024 * 1024 * 2);
    unsigned short* Rf1 = (unsigned short*)alloc((size_t)1024 * 1024 * 2);
    unsigned short* Rg1 = (unsigned short*)alloc((size_t)1024 * 1024 * 2);
    // contiguous zero-init region: ring0 | ring1 | flags0 | flags1 (padded)
    unsigned short* ring0 = (unsigned short*)alloc((size_t)8 * 64 * 1024 * 2); // 1 MB
    unsigned short* ring1 = (unsigned short*)alloc((size_t)2 * 64 * 1024 * 2); // 256 KB
    int* flags0 = (int*)alloc(64 * 32 * 4); // 8 KB: one 128B line per WG
    int* flags1 = (int*)alloc(64 * 32 * 4); // 8 KB

    // ws is poisoned every call: zero rings + padded flags in one memset
    hipMemsetAsync(ring0, 0, (size_t)1048576 + 262144 + 8192 + 8192, stream);

    auto cast = [&](const float* s, unsigned short* d, size_t n) {
        int n4 = (int)(n / 4);
        cast_f32_bf16<<<dim3((n4 + 255) / 256), dim3(256), 0, stream>>>(s, d, n4);
    };
    cast(X, Xb, (size_t)MROWS * 512);
    cast(ifW0, W0c, (size_t)1024 * 512);
    cast(igW0, W0c + (size_t)1024 * 512, (size_t)1024 * 512);
    cast(ifW1, W1c, (size_t)1024 * 1024);
    cast(igW1, W1c + (size_t)1024 * 1024, (size_t)1024 * 1024);
    cast(hfW0, Rf0, (size_t)1024 * 1024);
    cast(hgW0, Rg0, (size_t)1024 * 1024);
    cast(hfW1, Rf1, (size_t)1024 * 1024);
    cast(hgW1, Rg1, (size_t)1024 * 1024);

    // layer-0 input projections (layer 1's are computed on the fly in the fused kernel)
    gemm_bt_bias<<<dim3(MROWS / 128, 16), dim3(256), 0, stream>>>(Xb, W0c, ifB0, igB0, P, MROWS, 512);

    // fused two-layer pipelined scan: 64 WGs layer0 + 64 WGs layer1, 1-step skew
    janet_fused<<<dim3(128), dim3(256), 0, stream>>>(
        P, Rf0, Rg0, hfB0, hgB0,
        Rf1, Rg1, W1c, ifB1, hfB1, igB1, hgB1,
        ring0, ring1, flags0, flags1, (float*)d_out);
}